// Round 5
// baseline (403.897 us; speedup 1.0000x reference)
//
#include <hip/hip_runtime.h>
#include <hip/hip_bf16.h>

// Problem: B,T,D = 32,4096,128. Masked last/next-observation linear interp.
// Inputs: values/times bf16-converted (detected at runtime, fp32 also handled),
// mask bool8/int32/bf16/fp32 (detected). OUTPUT IS FLOAT32 (reference returns
// fp32; harness contract: non-bf16 output -> float*). Single kernel, no ws.
#define Bq 32
#define Tq 4096
#define Dq 128
#define Lseg 32
#define NSEG (Tq / Lseg)   // 128

__device__ __forceinline__ float bfbits2f(unsigned short u) {
    return __uint_as_float(((unsigned int)u) << 16);
}
__device__ __forceinline__ unsigned short f2bfbits(float x) {
    __hip_bfloat16 h = __float2bfloat16(x);
    return *(unsigned short*)&h;
}
__device__ __forceinline__ float ldval(const void* p, int idx, int f32) {
    if (f32) return ((const float*)p)[idx];
    return bfbits2f(((const unsigned short*)p)[idx]);
}
__device__ __forceinline__ bool ldmask(const void* p, int idx, int mode) {
    switch (mode) {
        case 1:  return ((const int*)p)[idx] != 0;            // int32 0/1
        case 2:  return ((const unsigned short*)p)[idx] != 0; // bf16 0/1.0
        case 3:  return ((const unsigned int*)p)[idx] != 0;   // fp32 0/1.0
        default: return ((const unsigned char*)p)[idx] != 0;  // bool8
    }
}

__global__ __launch_bounds__(128) void interp_kernel(
    const void* __restrict__ values,
    const void* __restrict__ times,
    const void* __restrict__ mask,
    float* __restrict__ out)                 // <-- fp32 output (THE fix)
{
    __shared__ float          s_nt[Lseg][Dq];   // next-observed time (fp32)
    __shared__ float          s_tm[Lseg][Dq];   // this row's time (fp32)
    __shared__ unsigned short s_nx[Lseg][Dq];   // next-observed value (bf16)
    __shared__ unsigned short s_vv[Lseg][Dq];   // this row's value (bf16)
    __shared__ unsigned char  s_m [Lseg][Dq];   // observed flag

    const int lane = threadIdx.x & 63;

    // ---- in-block dtype detection (wave-uniform, L2-hot) ----
    int mmode, f32;
    {
        const unsigned int* mu = (const unsigned int*)mask;
        int bad_f32 = 0, bad_b16 = 0, off_nz = 0;
        for (int j = lane; j < 1024; j += 64) {       // first 4096 bytes of mask
            unsigned int w = mu[j];
            if (w != 0u && w != 0x3F800000u) bad_f32 = 1;
            unsigned int h0 = w & 0xFFFFu, h1 = w >> 16;
            if ((h0 != 0u && h0 != 0x3F80u) || (h1 != 0u && h1 != 0x3F80u)) bad_b16 = 1;
            if (w & 0xFFFFFF00u) off_nz = 1;
        }
        if      (__ballot(bad_f32) == 0ull) mmode = 3;
        else if (__ballot(bad_b16) == 0ull) mmode = 2;
        else if (__ballot(off_nz)  == 0ull) mmode = 1;
        else                                mmode = 0;

        const unsigned short* tu = (const unsigned short*)times;
        int good = 0;
        for (int k = lane; k < 256; k += 64) {        // even u16s of first 256 elems
            int ex = (tu[2 * k] >> 7) & 0xFF;         // bf16 exponent field
            if (ex >= 118 && ex <= 142) good++;
        }
        for (int off = 32; off; off >>= 1) good += __shfl_xor(good, off, 64);
        f32 = (good < 128) ? 1 : 0;                   // bf16 passes ~100%, fp32 ~10%
    }

    const int b   = blockIdx.x >> 7;          // / NSEG
    const int s   = blockIdx.x & (NSEG - 1);
    const int d   = threadIdx.x;
    const int sLo = s * Lseg;
    const int sHi = sLo + Lseg;
    const int base = b * Tq * Dq + d;

    // ---- backward boundary: first observation at row >= sHi ----
    float bx = 0.f, bt;
    {
        int found = 0, nr = 0;
        int r = sHi;
        while (r < Tq && __ballot(!found) != 0ull) {
            bool m = ldmask(mask, base + r * Dq, mmode);
            if (!found && m) { nr = r; found = 1; }
            ++r;
        }
        if (found) {
            bx = ldval(values, base + nr * Dq, f32);
            bt = ldval(times,  base + nr * Dq, f32);
        } else {
            bt = ldval(times, base + (Tq - 1) * Dq, f32);   // t_max (monotone)
        }
    }

    // ---- forward boundary: last observation at row < sLo ----
    float fx = 0.f, ft;
    {
        int found = 0, nr = 0;
        int r = sLo - 1;
        while (r >= 0 && __ballot(!found) != 0ull) {
            bool m = ldmask(mask, base + r * Dq, mmode);
            if (!found && m) { nr = r; found = 1; }
            --r;
        }
        if (found) {
            fx = ldval(values, base + nr * Dq, f32);
            ft = ldval(times,  base + nr * Dq, f32);
        } else {
            ft = ldval(times, base + 0 * Dq, f32);          // times[b,0,d]
        }
    }

    // ---- backward sweep: fill per-row next-observation state into LDS ----
    #pragma unroll 8
    for (int rr = Lseg - 1; rr >= 0; --rr) {
        int idx = base + (sLo + rr) * Dq;
        float v  = ldval(values, idx, f32);
        float tm = ldval(times,  idx, f32);
        bool  m  = ldmask(mask,  idx, mmode);
        if (m) { bx = v; bt = tm; }
        s_nt[rr][d] = bt;
        s_nx[rr][d] = f2bfbits(bx);
        s_tm[rr][d] = tm;
        s_vv[rr][d] = f2bfbits(v);
        s_m [rr][d] = m ? 1 : 0;
    }
    // (no __syncthreads: each thread reads only its own column d)

    // ---- forward sweep: update last-observation state, emit fp32 ----
    #pragma unroll 8
    for (int rr = 0; rr < Lseg; ++rr) {
        float tm = s_tm[rr][d];
        float v  = bfbits2f(s_vv[rr][d]);
        bool  m  = s_m[rr][d] != 0;
        float ox;
        if (m) {
            fx = v; ft = tm;
            ox = v;
        } else {
            float nt = s_nt[rr][d];
            float nx = bfbits2f(s_nx[rr][d]);
            float denom = nt - ft;
            float num = fx * (nt - tm) + nx * (tm - ft);
            ox = (denom != 0.f) ? (num / denom) : 0.f;
        }
        out[base + (sLo + rr) * Dq] = ox;     // fp32 store
    }
}

extern "C" void kernel_launch(void* const* d_in, const int* in_sizes, int n_in,
                              void* d_out, int out_size, void* d_ws, size_t ws_size,
                              hipStream_t stream) {
    const void* values = d_in[0];
    const void* times  = d_in[1];
    const void* mask   = d_in[2];
    float* out = (float*)d_out;               // reference output dtype = float32
    (void)d_ws; (void)ws_size;

    interp_kernel<<<Bq * NSEG, 128, 0, stream>>>(values, times, mask, out);
}